// Round 1
// baseline (266.874 us; speedup 1.0000x reference)
//
#include <hip/hip_runtime.h>

#define HLr 32
#define HHr 64
#define NEG_INF -1000000000.0f
constexpr float LOG2E = 1.4426950408889634f;

// ---------------- offset table: all (dx,dy,dz) with r2<=9, sorted by r2 ----------------
struct OffTable { int dx[123]; int dy[123]; int dz[123]; int r2[123]; };
constexpr OffTable make_offsets() {
    OffTable t{};
    int n = 0;
    for (int rr = 0; rr <= 9; ++rr)
        for (int a = -3; a <= 3; ++a)
            for (int b = -3; b <= 3; ++b)
                for (int c = -3; c <= 3; ++c)
                    if (a*a + b*b + c*c == rr) {
                        t.dx[n] = a; t.dy[n] = b; t.dz[n] = c; t.r2[n] = rr; ++n;
                    }
    return t;
}
__constant__ OffTable OFFS = make_offsets();

__device__ __forceinline__ float fast_exp2(float x) { return __builtin_amdgcn_exp2f(x); }

// ---------------- prep A: per-LR-voxel sigma reciprocals + sigma_eff ----------------
__global__ void prepA(const float* __restrict__ sxr, const float* __restrict__ syr,
                      const float* __restrict__ szr, const float* __restrict__ srr,
                      float4* __restrict__ cellA, float* __restrict__ sigEff) {
    int t = blockIdx.x * 256 + threadIdx.x;   // 32768 total
    float sx = fmaxf(expf(sxr[t]), 1e-6f);
    float sy = fmaxf(expf(syr[t]), 1e-6f);
    float sz = fmaxf(expf(szr[t]), 1e-6f);
    float sr = fmaxf(expf(srr[t]), 1e-6f);
    float a = 0.5f / (sx * sx);
    float b = 0.5f / (sy * sy);
    float c = 0.5f / (sz * sz);
    float d = 1.0f / (2.0f * sr * sr + 1e-8f);
    cellA[t] = make_float4(a, b, c, d);
    sigEff[t] = fmaxf(sx, fmaxf(sy, sz));
}

// ---------------- prep B: guide 64^3 -> 32^3 trilinear-antialias downsample ----------------
__device__ __forceinline__ void mk_taps(int j, int idx[4], float wt[4]) {
    float s = 0.f;
#pragma unroll
    for (int k = 0; k < 4; ++k) {
        int i = 2 * j - 1 + k;
        float w = (k == 0 || k == 3) ? 0.25f : 0.75f;
        bool ok = (i >= 0) && (i < 64);
        wt[k] = ok ? w : 0.f;
        idx[k] = ok ? i : 0;
        s += wt[k];
    }
    float inv = 1.f / s;
#pragma unroll
    for (int k = 0; k < 4; ++k) wt[k] *= inv;
}

__global__ void prepB(const float* __restrict__ guide, float4* __restrict__ cellB) {
    int t = blockIdx.x * 256 + threadIdx.x;   // 32768 total
    int w = t & 31, v = (t >> 5) & 31, u = t >> 10;
    int iu[4], iv[4], iw[4];
    float wu[4], wv[4], ww[4];
    mk_taps(u, iu, wu);
    mk_taps(v, iv, wv);
    mk_taps(w, iw, ww);
    float g0 = 0.f, g1 = 0.f, g2 = 0.f;
#pragma unroll
    for (int a = 0; a < 4; ++a) {
#pragma unroll
        for (int b = 0; b < 4; ++b) {
            float wab = wu[a] * wv[b];
            int base = iu[a] * 4096 + iv[b] * 64;
#pragma unroll
            for (int c = 0; c < 4; ++c) {
                float wt = wab * ww[c];
                int gi = base + iw[c];
                g0 += wt * guide[gi];
                g1 += wt * guide[262144 + gi];
                g2 += wt * guide[524288 + gi];
            }
        }
    }
    cellB[t] = make_float4(g0, g1, g2, 0.f);
}

// ---------------- prep T: feat [c][u][v][w] -> featT [u][v][w][c] ----------------
__global__ void prepT(const float* __restrict__ feat, float* __restrict__ featT) {
    __shared__ float tile[32][33];
    int uv = blockIdx.x;            // 1024 blocks, one per (u,v)
    int u = uv >> 5, v = uv & 31;
    int col = threadIdx.x & 31;
    int row = threadIdx.x >> 5;     // 0..7
#pragma unroll
    for (int it = 0; it < 4; ++it) {
        int c = row + it * 8;
        tile[c][col] = feat[((c * 32 + u) * 32 + v) * 32 + col];
    }
    __syncthreads();
#pragma unroll
    for (int it = 0; it < 4; ++it) {
        int w = row + it * 8;
        featT[((u * 32 + v) * 32 + w) * 32 + col] = tile[col][w];
    }
}

// ---------------- main kernel: one thread per HR voxel ----------------
__global__ __launch_bounds__(256)
void jbu_main(const float* __restrict__ guide, const float4* __restrict__ cellA,
              const float4* __restrict__ cellB, const float* __restrict__ sigEff,
              const float* __restrict__ featT, float* __restrict__ out) {
    int t = blockIdx.x * 256 + threadIdx.x;   // t == X*4096 + Y*64 + Z
    int Z = t & 63, Y = (t >> 6) & 63, X = t >> 12;

    float G0 = guide[t];
    float G1 = guide[262144 + t];
    float G2 = guide[524288 + t];

    // sigma_eff_hr: 2x trilinear upsample with clamped taps
    int x0 = max((X - 1) >> 1, 0), x1 = min(((X - 1) >> 1) + 1, 31);
    int y0 = max((Y - 1) >> 1, 0), y1 = min(((Y - 1) >> 1) + 1, 31);
    int z0 = max((Z - 1) >> 1, 0), z1 = min(((Z - 1) >> 1) + 1, 31);
    float wx1 = (X & 1) ? 0.25f : 0.75f, wx0 = 1.f - wx1;
    float wy1 = (Y & 1) ? 0.25f : 0.75f, wy0 = 1.f - wy1;
    float wz1 = (Z & 1) ? 0.25f : 0.75f, wz0 = 1.f - wz1;
#define SG(i, j, k) sigEff[((i) * 32 + (j)) * 32 + (k)]
    float se =
        wx0 * (wy0 * (wz0 * SG(x0, y0, z0) + wz1 * SG(x0, y0, z1)) +
               wy1 * (wz0 * SG(x0, y1, z0) + wz1 * SG(x0, y1, z1))) +
        wx1 * (wy0 * (wz0 * SG(x1, y0, z0) + wz1 * SG(x1, y0, z1)) +
               wy1 * (wz0 * SG(x1, y1, z0) + wz1 * SG(x1, y1, z1)));
#undef SG
    float Rf = fminf(fmaxf(ceilf(2.f * se), 1.f), 3.f);
    int R2i = (int)(Rf * Rf + 0.5f);

    // wave-uniform loop bound (offsets sorted by r2)
    int R2w = R2i;
#pragma unroll
    for (int s = 32; s; s >>= 1) R2w = max(R2w, __shfl_xor(R2w, s));
    int nmax = (R2w >= 9) ? 123 : ((R2w >= 4) ? 33 : 7);

    int uc = X >> 1, vc = Y >> 1, wc = Z >> 1;
    float Xh = (float)X - 0.5f, Yh = (float)Y - 0.5f, Zh = (float)Z - 0.5f;

    float m = NEG_INF, den = 0.f;
    float num[32];
#pragma unroll
    for (int c = 0; c < 32; ++c) num[c] = 0.f;

    for (int o = 0; o < nmax; ++o) {
        int r2 = OFFS.r2[o];
        int Ui = min(max(uc + OFFS.dx[o], 0), 31);
        int Vi = min(max(vc + OFFS.dy[o], 0), 31);
        int Wi = min(max(wc + OFFS.dz[o], 0), 31);
        int ci = (Ui * 32 + Vi) * 32 + Wi;
        float4 ab = cellA[ci];
        float4 gl = cellB[ci];
        float ddx = Xh - 2.f * (float)Ui;
        float ddy = Yh - 2.f * (float)Vi;
        float ddz = Zh - 2.f * (float)Wi;
        float lw = -(ddx * ddx * ab.x + ddy * ddy * ab.y + ddz * ddz * ab.z);
        float d0 = G0 - gl.x, d1 = G1 - gl.y, d2 = G2 - gl.z;
        lw -= (d0 * d0 + d1 * d1 + d2 * d2) * ab.w;
        if (r2 <= R2i) {
            if (lw > m) {
                float sc = fast_exp2((m - lw) * LOG2E);
                den *= sc;
#pragma unroll
                for (int c = 0; c < 32; ++c) num[c] *= sc;
                m = lw;
            }
            float wgt = fast_exp2((lw - m) * LOG2E);
            den += wgt;
            const float4* fp = reinterpret_cast<const float4*>(featT + (size_t)ci * 32);
#pragma unroll
            for (int q = 0; q < 8; ++q) {
                float4 f = fp[q];
                num[4 * q + 0] += wgt * f.x;
                num[4 * q + 1] += wgt * f.y;
                num[4 * q + 2] += wgt * f.z;
                num[4 * q + 3] += wgt * f.w;
            }
        }
    }

    float inv = 1.f / fmaxf(den, 1e-8f);
#pragma unroll
    for (int c = 0; c < 32; ++c) out[c * 262144 + t] = num[c] * inv;
}

// ---------------- launch ----------------
extern "C" void kernel_launch(void* const* d_in, const int* in_sizes, int n_in,
                              void* d_out, int out_size, void* d_ws, size_t ws_size,
                              hipStream_t stream) {
    const float* feat = (const float*)d_in[0];    // [1][32][32][32][32]
    const float* guide = (const float*)d_in[1];   // [1][3][64][64][64]
    const float* sxr = (const float*)d_in[2];
    const float* syr = (const float*)d_in[3];
    const float* szr = (const float*)d_in[4];
    const float* srr = (const float*)d_in[5];
    float* out = (float*)d_out;                   // [1][32][64][64][64]

    char* ws = (char*)d_ws;
    float4* cellA = (float4*)ws;                       // 32768 * 16 = 524288 B
    float4* cellB = (float4*)(ws + 524288);            // 524288 B
    float* sigEff = (float*)(ws + 1048576);            // 131072 B
    float* featT = (float*)(ws + 1179648);             // 4 MB

    prepA<<<128, 256, 0, stream>>>(sxr, syr, szr, srr, cellA, sigEff);
    prepB<<<128, 256, 0, stream>>>(guide, cellB);
    prepT<<<1024, 256, 0, stream>>>(feat, featT);
    jbu_main<<<1024, 256, 0, stream>>>(guide, cellA, cellB, sigEff, featT, out);
}